// Round 7
// baseline (384.918 us; speedup 1.0000x reference)
//
#include <hip/hip_runtime.h>

typedef float  f32x4 __attribute__((ext_vector_type(4)));
typedef short  s16x8 __attribute__((ext_vector_type(8)));

#define PK   256   // panel K-span (floats); 1KB burst per row
#define PSTR 260   // padded LDS row stride

typedef const __attribute__((address_space(1))) float* gas1f;
typedef __attribute__((address_space(3))) float*       las3f;

__device__ __forceinline__ short f2bf(float f) {
  unsigned u = __builtin_bit_cast(unsigned, f);
  u += 0x7FFFu + ((u >> 16) & 1u);   // round-to-nearest-even
  return (short)(u >> 16);
}

// ---------------------------------------------------------------------------
// Kernel 1: Y^T build.  Yt[c][k] = bf16( sum_d x[k][d] * W[d][c] )
// Kpad multiple of 256, zero-filled.  Offsets (elements):
//  v2v 0 (Kpad 6144) | v2e 196608 | e2e 393216 (Kpad 12032) | e2f 778240
//  f2f 1163264 (Kpad 8192); total 1425408 elems = 2.85 MB.
// ---------------------------------------------------------------------------
__global__ __launch_bounds__(256) void build_yt(
    const float* __restrict__ xv, const float* __restrict__ xe,
    const float* __restrict__ xf,
    const float* __restrict__ Wv2v, const float* __restrict__ Wv2e,
    const float* __restrict__ We2e, const float* __restrict__ We2f,
    const float* __restrict__ Wf2f, short* __restrict__ Yt)
{
  int bid = blockIdx.x;
  const float* x; const float* W; int K, Kpad; size_t yoff;
  if (bid < 24)       { x=xv; W=Wv2v; K=6000;  Kpad=6144;  yoff=0;       }
  else if (bid < 48)  { x=xv; W=Wv2e; K=6000;  Kpad=6144;  yoff=196608;  bid-=24; }
  else if (bid < 95)  { x=xe; W=We2e; K=12000; Kpad=12032; yoff=393216;  bid-=48; }
  else if (bid < 142) { x=xe; W=We2f; K=12000; Kpad=12032; yoff=778240;  bid-=95; }
  else                { x=xf; W=Wf2f; K=8000;  Kpad=8192;  yoff=1163264; bid-=142; }

  __shared__ float Wl[32][32];
  int tid = threadIdx.x;
  #pragma unroll
  for (int i = 0; i < 4; ++i) {
    int e = tid + i * 256;
    Wl[e >> 5][e & 31] = W[e];
  }
  __syncthreads();

  int row = bid * 256 + tid;
  if (row >= Kpad) return;

  float acc[32];
  #pragma unroll
  for (int c = 0; c < 32; ++c) acc[c] = 0.f;

  if (row < K) {
    const float* xp = x + (size_t)row * 32;
    float xr[32];
    #pragma unroll
    for (int i = 0; i < 8; ++i) {
      f32x4 v = *(const f32x4*)(xp + i * 4);
      xr[i*4+0] = v.x; xr[i*4+1] = v.y; xr[i*4+2] = v.z; xr[i*4+3] = v.w;
    }
    #pragma unroll
    for (int d = 0; d < 32; ++d) {
      float xd = xr[d];
      #pragma unroll
      for (int c = 0; c < 32; ++c) acc[c] += xd * Wl[d][c];
    }
  }
  #pragma unroll
  for (int c = 0; c < 32; ++c)
    Yt[yoff + (size_t)c * Kpad + row] = f2bf(acc[c]);
}

// ---------------------------------------------------------------------------
// Kernel 2: skinny GEMM, K-CHUNKED for tail smoothing.
// R4 pipeline (counted vmcnt, B reg-prefetch, aux=0): each block owns one
// 16x32 output tile x one single-segment K-chunk of 16-24 panels.
// Chunk 0 writes out directly; chunks >=1 write 512-float partials to ws.
// ---------------------------------------------------------------------------
__device__ __forceinline__ void stage_panel(
    const float* __restrict__ G, int K, int row0, int pn, int lane, int w,
    float (*panel)[16][PSTR], int bb)
{
  if ((pn + 1) * PK <= K) {            // full panel: 1KB DMA burst per row
    const float* base = G + (size_t)row0 * K + (size_t)pn * PK;
    #pragma unroll
    for (int j = 0; j < 4; ++j) {
      int rr = 4 * w + j;
      __builtin_amdgcn_global_load_lds((gas1f)(base + (size_t)rr * K + lane * 4),
                                       (las3f)&panel[bb][rr][0], 16, 0, 0);
    }
  } else {                             // tail: reg-staged, masked, zero-filled
    #pragma unroll
    for (int j = 0; j < 4; ++j) {
      int rr = 4 * w + j;
      int k = pn * PK + lane * 4;
      f32x4 v = {0.f, 0.f, 0.f, 0.f};
      if (k < K) v = *(const f32x4*)(G + (size_t)(row0 + rr) * K + k);
      *(f32x4*)&panel[bb][rr][lane * 4] = v;
    }
  }
}

__device__ __forceinline__ void loadB(const short* __restrict__ Y, int Kp,
                                      int r, int g, int w, int p, s16x8 B[2][2])
{
  #pragma unroll
  for (int si = 0; si < 2; ++si) {
    int kg = p * PK + (2 * w + si) * 32 + g * 8;
    B[si][0] = *(const s16x8*)(Y + (size_t)r        * Kp + kg);
    B[si][1] = *(const s16x8*)(Y + (size_t)(r + 16) * Kp + kg);
  }
}

__device__ __forceinline__ void seg_run(
    const float* __restrict__ G, const short* __restrict__ Yt,
    int K, int Kp, int row0, int p_lo, int p_hi, int lane, int w,
    float (*panel)[16][PSTR], f32x4& acc0, f32x4& acc1)
{
  int r = lane & 15, g = lane >> 4;
  s16x8 Bc[2][2], Bn[2][2];

  // prologue, FIFO order: stage(p_lo) < B(p_lo) < stage(p_lo+1)
  stage_panel(G, K, row0, p_lo, lane, w, panel, p_lo & 1);
  loadB(Yt, Kp, r, g, w, p_lo, Bc);
  if (p_lo + 1 < p_hi) stage_panel(G, K, row0, p_lo + 1, lane, w, panel, (p_lo + 1) & 1);

  for (int p = p_lo; p < p_hi; ++p) {
    // wait: stage(p)+B(p) done; stage(p+1) (if DMA-staged) stays in flight
    if (p + 1 < p_hi && (p + 2) * PK <= K)
      asm volatile("s_waitcnt vmcnt(4)" ::: "memory");
    else
      asm volatile("s_waitcnt vmcnt(0)" ::: "memory");
    __builtin_amdgcn_s_barrier();

    int b = p & 1;
    const float* rowp = &panel[b][r][0];
    #pragma unroll
    for (int si = 0; si < 2; ++si) {
      int kk = (2 * w + si) * 32 + g * 8;
      f32x4 a0 = *(const f32x4*)(rowp + kk);
      f32x4 a1 = *(const f32x4*)(rowp + kk + 4);
      s16x8 a;
      a[0] = f2bf(a0.x); a[1] = f2bf(a0.y); a[2] = f2bf(a0.z); a[3] = f2bf(a0.w);
      a[4] = f2bf(a1.x); a[5] = f2bf(a1.y); a[6] = f2bf(a1.z); a[7] = f2bf(a1.w);
      acc0 = __builtin_amdgcn_mfma_f32_16x16x32_bf16(a, Bc[si][0], acc0, 0, 0, 0);
      acc1 = __builtin_amdgcn_mfma_f32_16x16x32_bf16(a, Bc[si][1], acc1, 0, 0, 0);
    }

    bool have_next = (p + 1 < p_hi);
    if (have_next) loadB(Yt, Kp, r, g, w, p + 1, Bn);   // flies across barrier

    asm volatile("s_waitcnt lgkmcnt(0)" ::: "memory");
    __builtin_amdgcn_sched_barrier(0);
    __builtin_amdgcn_s_barrier();      // all waves done reading buf b
    if (p + 2 < p_hi) stage_panel(G, K, row0, p + 2, lane, w, panel, b);

    if (have_next) {
      #pragma unroll
      for (int si = 0; si < 2; ++si) {
        Bc[si][0] = Bn[si][0]; Bc[si][1] = Bn[si][1];
      }
    }
  }
  __syncthreads();                     // chunk epilogue: full drain
}

// grid = 4625: zf 2000 (4 chunks/tile), ze 2250 (3), zv 375 (1)
__global__ __launch_bounds__(256) void gemm_skinny(
    const float* __restrict__ Gv2v, const float* __restrict__ Gv2e,
    const float* __restrict__ Ge2e, const float* __restrict__ Ge2f,
    const float* __restrict__ Gf2f, const short* __restrict__ Yt,
    float* __restrict__ part, float* __restrict__ out)
{
  __shared__ float panel[2][16][PSTR];   // 33,280 B; reused for reduce

  int bid  = blockIdx.x;
  int lane = threadIdx.x & 63, w = threadIdx.x >> 6;

  const float* G; const short* Y; int K, Kp, p_lo, p_hi, tile;
  float* dst;
  if (bid < 2000) {              // zf = Ge2f@Ye2f + Gf2f@Yf2f
    tile = bid >> 2; int c = bid & 3;
    if (c < 2) { G = Ge2f; Y = Yt + 778240;  K = 12000; Kp = 12032;
                 p_lo = c ? 24 : 0;        p_hi = c ? 47 : 24; }
    else       { G = Gf2f; Y = Yt + 1163264; K = 8000;  Kp = 8192;
                 p_lo = (c == 3) ? 16 : 0; p_hi = (c == 3) ? 32 : 16; }
    dst = (c == 0) ? out + 576000 + (size_t)tile * 512
                   : part + (size_t)(tile * 3 + (c - 1)) * 512;
  } else if (bid < 4250) {       // ze = Gv2e@Yv2e + Ge2e@Ye2e
    int t2 = bid - 2000; tile = t2 / 3; int c = t2 - tile * 3;
    if (c == 0) { G = Gv2e; Y = Yt + 196608; K = 6000;  Kp = 6144;
                  p_lo = 0;  p_hi = 24; }
    else        { G = Ge2e; Y = Yt + 393216; K = 12000; Kp = 12032;
                  p_lo = (c == 2) ? 24 : 0; p_hi = (c == 2) ? 47 : 24; }
    dst = (c == 0) ? out + 192000 + (size_t)tile * 512
                   : part + (size_t)(1500 + tile * 2 + (c - 1)) * 512;
  } else {                       // zv = Gv2v@Yv2v (single chunk)
    tile = bid - 4250;
    G = Gv2v; Y = Yt; K = 6000; Kp = 6144; p_lo = 0; p_hi = 24;
    dst = out + (size_t)tile * 512;
  }
  int row0 = tile * 16;

  f32x4 acc0 = {0.f,0.f,0.f,0.f}, acc1 = {0.f,0.f,0.f,0.f};
  seg_run(G, Y, K, Kp, row0, p_lo, p_hi, lane, w, panel, acc0, acc1);

  // cross-wave reduce (C/D layout: col = lane&15, row = (lane>>4)*4+reg)
  float (*red)[512] = (float (*)[512])panel;   // safe: seg_run ends synced
  int r = lane & 15, g = lane >> 4;
  #pragma unroll
  for (int q = 0; q < 4; ++q) {
    int rw = g * 4 + q;
    red[w][rw * 32 + r]      = acc0[q];
    red[w][rw * 32 + 16 + r] = acc1[q];
  }
  __syncthreads();
  #pragma unroll
  for (int i = 0; i < 2; ++i) {
    int e = (int)threadIdx.x + i * 256;
    dst[e] = red[0][e] + red[1][e] + red[2][e] + red[3][e];
  }
}

// Sum partials into out. zf: 3 partials/tile; ze: 2 partials/tile.
__global__ __launch_bounds__(256) void reduce_partials(
    float* __restrict__ out, const float* __restrict__ part)
{
  int e = blockIdx.x * 256 + threadIdx.x;
  if (e < 256000) {                    // zf: 500 tiles x 512
    int tile = e >> 9, wi = e & 511;
    const float* p = part + (size_t)tile * 3 * 512;
    out[576000 + e] += p[wi] + p[512 + wi] + p[1024 + wi];
  } else if (e < 640000) {             // ze: 750 tiles x 512
    int e2 = e - 256000;
    int t = e2 >> 9, wi = e2 & 511;
    const float* p = part + (size_t)(1500 + t * 2) * 512;
    out[192000 + e2] += p[wi] + p[512 + wi];
  }
}

extern "C" void kernel_launch(void* const* d_in, const int* in_sizes, int n_in,
                              void* d_out, int out_size, void* d_ws, size_t ws_size,
                              hipStream_t stream) {
  const float* xv   = (const float*)d_in[0];
  const float* xe   = (const float*)d_in[1];
  const float* xf   = (const float*)d_in[2];
  const float* Gv2v = (const float*)d_in[3];
  const float* Gv2e = (const float*)d_in[4];
  const float* Ge2e = (const float*)d_in[5];
  const float* Ge2f = (const float*)d_in[6];
  const float* Gf2f = (const float*)d_in[7];
  const float* Wv2v = (const float*)d_in[8];
  const float* Wv2e = (const float*)d_in[9];
  const float* We2e = (const float*)d_in[10];
  const float* We2f = (const float*)d_in[11];
  const float* Wf2f = (const float*)d_in[12];
  short* Yt   = (short*)d_ws;
  float* part = (float*)((char*)d_ws + 2850816);   // after Yt (1425408 shorts)
  float* out  = (float*)d_out;

  hipLaunchKernelGGL(build_yt, dim3(174), dim3(256), 0, stream,
                     xv, xe, xf, Wv2v, Wv2e, We2e, We2f, Wf2f, Yt);
  hipLaunchKernelGGL(gemm_skinny, dim3(4625), dim3(256), 0, stream,
                     Gv2v, Gv2e, Ge2e, Ge2f, Gf2f, Yt, part, out);
  hipLaunchKernelGGL(reduce_partials, dim3(2500), dim3(256), 0, stream,
                     out, part);
}

// Round 8
// 316.509 us; speedup vs baseline: 1.2161x; 1.2161x over previous
//
#include <hip/hip_runtime.h>

typedef float  f32x4 __attribute__((ext_vector_type(4)));
typedef short  s16x8 __attribute__((ext_vector_type(8)));

#define PK   256   // panel K-span (floats); 1KB burst per row
#define PSTR 260   // padded LDS row stride (2-way bank alias = free)
#define TM   32    // output rows per block

typedef const __attribute__((address_space(1))) float* gas1f;
typedef __attribute__((address_space(3))) float*       las3f;

__device__ __forceinline__ short f2bf(float f) {
  unsigned u = __builtin_bit_cast(unsigned, f);
  u += 0x7FFFu + ((u >> 16) & 1u);   // round-to-nearest-even
  return (short)(u >> 16);
}

// ---------------------------------------------------------------------------
// Kernel 1: Y^T build.  Yt[c][k] = bf16( sum_d x[k][d] * W[d][c] )
// Kpad multiple of 256, zero-filled.  Offsets (elements):
//  v2v 0 (Kpad 6144) | v2e 196608 | e2e 393216 (Kpad 12032) | e2f 778240
//  f2f 1163264 (Kpad 8192); total 1425408 elems = 2.85 MB.
// ---------------------------------------------------------------------------
__global__ __launch_bounds__(256) void build_yt(
    const float* __restrict__ xv, const float* __restrict__ xe,
    const float* __restrict__ xf,
    const float* __restrict__ Wv2v, const float* __restrict__ Wv2e,
    const float* __restrict__ We2e, const float* __restrict__ We2f,
    const float* __restrict__ Wf2f, short* __restrict__ Yt)
{
  int bid = blockIdx.x;
  const float* x; const float* W; int K, Kpad; size_t yoff;
  if (bid < 24)       { x=xv; W=Wv2v; K=6000;  Kpad=6144;  yoff=0;       }
  else if (bid < 48)  { x=xv; W=Wv2e; K=6000;  Kpad=6144;  yoff=196608;  bid-=24; }
  else if (bid < 95)  { x=xe; W=We2e; K=12000; Kpad=12032; yoff=393216;  bid-=48; }
  else if (bid < 142) { x=xe; W=We2f; K=12000; Kpad=12032; yoff=778240;  bid-=95; }
  else                { x=xf; W=Wf2f; K=8000;  Kpad=8192;  yoff=1163264; bid-=142; }

  __shared__ float Wl[32][32];
  int tid = threadIdx.x;
  #pragma unroll
  for (int i = 0; i < 4; ++i) {
    int e = tid + i * 256;
    Wl[e >> 5][e & 31] = W[e];
  }
  __syncthreads();

  int row = bid * 256 + tid;
  if (row >= Kpad) return;

  float acc[32];
  #pragma unroll
  for (int c = 0; c < 32; ++c) acc[c] = 0.f;

  if (row < K) {
    const float* xp = x + (size_t)row * 32;
    float xr[32];
    #pragma unroll
    for (int i = 0; i < 8; ++i) {
      f32x4 v = *(const f32x4*)(xp + i * 4);
      xr[i*4+0] = v.x; xr[i*4+1] = v.y; xr[i*4+2] = v.z; xr[i*4+3] = v.w;
    }
    #pragma unroll
    for (int d = 0; d < 32; ++d) {
      float xd = xr[d];
      #pragma unroll
      for (int c = 0; c < 32; ++c) acc[c] += xd * Wl[d][c];
    }
  }
  #pragma unroll
  for (int c = 0; c < 32; ++c)
    Yt[yoff + (size_t)c * Kpad + row] = f2bf(acc[c]);
}

// ---------------------------------------------------------------------------
// Kernel 2: skinny GEMM, TM=32 (halves B-side L2/L3 traffic vs TM=16).
// 512 threads / 8 waves. Per panel [32][256]f: each wave DMA-stages 4 rows
// (1KB contiguous bursts, nt) and computes 1 k-step (4 MFMAs: {lo,hi} rows
// x {0,1} col-groups). Counted-vmcnt pipeline: stage(p+1) stays in flight
// across the compute of p; B (Yt) reg-prefetched one panel ahead.
// ---------------------------------------------------------------------------
__device__ __forceinline__ void stage_panel(
    const float* __restrict__ G, int K, int row0, int pn, int lane, int w,
    float (*panel)[TM][PSTR], int bb)
{
  if ((pn + 1) * PK <= K) {            // full panel: 1KB DMA burst per row
    const float* base = G + (size_t)row0 * K + (size_t)pn * PK;
    #pragma unroll
    for (int j = 0; j < 4; ++j) {
      int rr = 4 * w + j;              // 8 waves x 4 rows = 32
      __builtin_amdgcn_global_load_lds((gas1f)(base + (size_t)rr * K + lane * 4),
                                       (las3f)&panel[bb][rr][0], 16, 0, 2 /*nt*/);
    }
  } else {                             // tail: reg-staged, masked, zero-filled
    #pragma unroll
    for (int j = 0; j < 4; ++j) {
      int rr = 4 * w + j;
      int k = pn * PK + lane * 4;
      f32x4 v = {0.f, 0.f, 0.f, 0.f};
      if (k < K) v = *(const f32x4*)(G + (size_t)(row0 + rr) * K + k);
      *(f32x4*)&panel[bb][rr][lane * 4] = v;
    }
  }
}

__device__ __forceinline__ void loadB(const short* __restrict__ Y, int Kp,
                                      int r, int g, int w, int p, s16x8 B[2])
{
  int kg = p * PK + w * 32 + g * 8;    // wave w owns k-step w of the panel
  B[0] = *(const s16x8*)(Y + (size_t)r        * Kp + kg);
  B[1] = *(const s16x8*)(Y + (size_t)(r + 16) * Kp + kg);
}

__device__ __forceinline__ void seg_run(
    const float* __restrict__ G, const short* __restrict__ Yt,
    int K, int Kp, int np, int row0, int lane, int w,
    float (*panel)[TM][PSTR],
    f32x4& acc00, f32x4& acc01, f32x4& acc10, f32x4& acc11)
{
  int r = lane & 15, g = lane >> 4;
  s16x8 Bc[2], Bn[2];

  // prologue, per-wave FIFO: stage(0)[4] < B(0)[2] < stage(1)[4]
  stage_panel(G, K, row0, 0, lane, w, panel, 0);
  loadB(Yt, Kp, r, g, w, 0, Bc);
  if (np > 1) stage_panel(G, K, row0, 1, lane, w, panel, 1);

  for (int p = 0; p < np; ++p) {
    // wait: stage(p)+B(p) done; stage(p+1) (if DMA-staged) stays in flight
    if (p + 1 < np && (p + 2) * PK <= K)
      asm volatile("s_waitcnt vmcnt(4)" ::: "memory");
    else
      asm volatile("s_waitcnt vmcnt(0)" ::: "memory");
    __builtin_amdgcn_s_barrier();

    int b  = p & 1;
    int kk = w * 32 + g * 8;
    f32x4 l0 = *(const f32x4*)&panel[b][r][kk];
    f32x4 l1 = *(const f32x4*)&panel[b][r][kk + 4];
    f32x4 h0 = *(const f32x4*)&panel[b][r + 16][kk];
    f32x4 h1 = *(const f32x4*)&panel[b][r + 16][kk + 4];
    s16x8 alo, ahi;
    alo[0]=f2bf(l0.x); alo[1]=f2bf(l0.y); alo[2]=f2bf(l0.z); alo[3]=f2bf(l0.w);
    alo[4]=f2bf(l1.x); alo[5]=f2bf(l1.y); alo[6]=f2bf(l1.z); alo[7]=f2bf(l1.w);
    ahi[0]=f2bf(h0.x); ahi[1]=f2bf(h0.y); ahi[2]=f2bf(h0.z); ahi[3]=f2bf(h0.w);
    ahi[4]=f2bf(h1.x); ahi[5]=f2bf(h1.y); ahi[6]=f2bf(h1.z); ahi[7]=f2bf(h1.w);
    acc00 = __builtin_amdgcn_mfma_f32_16x16x32_bf16(alo, Bc[0], acc00, 0, 0, 0);
    acc01 = __builtin_amdgcn_mfma_f32_16x16x32_bf16(alo, Bc[1], acc01, 0, 0, 0);
    acc10 = __builtin_amdgcn_mfma_f32_16x16x32_bf16(ahi, Bc[0], acc10, 0, 0, 0);
    acc11 = __builtin_amdgcn_mfma_f32_16x16x32_bf16(ahi, Bc[1], acc11, 0, 0, 0);

    bool have_next = (p + 1 < np);
    if (have_next) loadB(Yt, Kp, r, g, w, p + 1, Bn);   // flies across barrier

    asm volatile("s_waitcnt lgkmcnt(0)" ::: "memory");
    __builtin_amdgcn_sched_barrier(0);
    __builtin_amdgcn_s_barrier();      // all waves done reading buf b
    if (p + 2 < np) stage_panel(G, K, row0, p + 2, lane, w, panel, b);

    if (have_next) { Bc[0] = Bn[0]; Bc[1] = Bn[1]; }
  }
  __syncthreads();                     // segment epilogue: full drain
}

// grid = 813: zf 250 (heaviest, 79 panels) | ze 375 (71) | zv 188 (24)
__global__ __launch_bounds__(512) void gemm_skinny(
    const float* __restrict__ Gv2v, const float* __restrict__ Gv2e,
    const float* __restrict__ Ge2e, const float* __restrict__ Ge2f,
    const float* __restrict__ Gf2f, const short* __restrict__ Yt,
    float* __restrict__ out)
{
  __shared__ float panel[2][TM][PSTR];   // 66,560 B; reused for reduce

  int bid  = blockIdx.x;
  int lane = threadIdx.x & 63, w = threadIdx.x >> 6;

  const float *G0, *G1; const short *Y0, *Y1;
  int K0, Kp0, n0, K1, Kp1, n1, tile; size_t ob;
  if (bid < 250) {           // zf = Ge2f@Ye2f + Gf2f@Yf2f
    tile = bid;
    G0 = Ge2f; Y0 = Yt + 778240;  K0 = 12000; Kp0 = 12032; n0 = 47;
    G1 = Gf2f; Y1 = Yt + 1163264; K1 = 8000;  Kp1 = 8192;  n1 = 32;
    ob = 576000;
  } else if (bid < 625) {    // ze = Gv2e@Yv2e + Ge2e@Ye2e
    tile = bid - 250;
    G0 = Gv2e; Y0 = Yt + 196608;  K0 = 6000;  Kp0 = 6144;  n0 = 24;
    G1 = Ge2e; Y1 = Yt + 393216;  K1 = 12000; Kp1 = 12032; n1 = 47;
    ob = 192000;
  } else {                   // zv = Gv2v@Yv2v
    tile = bid - 625;        // 0..187; last tile overlaps (rows 5968-5999)
    G0 = Gv2v; Y0 = Yt;           K0 = 6000;  Kp0 = 6144;  n0 = 24;
    G1 = nullptr; Y1 = nullptr;   K1 = 0; Kp1 = 0; n1 = 0;
    ob = 0;
  }
  int row0 = tile * TM;
  if (!G1 && row0 + TM > 6000) row0 = 6000 - TM;   // zv overlap tile

  f32x4 acc00 = {0.f,0.f,0.f,0.f}, acc01 = {0.f,0.f,0.f,0.f};
  f32x4 acc10 = {0.f,0.f,0.f,0.f}, acc11 = {0.f,0.f,0.f,0.f};
  seg_run(G0, Y0, K0, Kp0, n0, row0, lane, w, panel, acc00, acc01, acc10, acc11);
  if (G1)
    seg_run(G1, Y1, K1, Kp1, n1, row0, lane, w, panel, acc00, acc01, acc10, acc11);

  // cross-wave reduce (C/D layout: col = lane&15, row = (lane>>4)*4+reg)
  float (*red)[1024] = (float (*)[1024])panel;   // 8x1024 f = 32KB, aliases panel
  int r = lane & 15, g = lane >> 4;
  #pragma unroll
  for (int q = 0; q < 4; ++q) {
    int rl = g * 4 + q;
    red[w][ rl       * 32 +      r] = acc00[q];
    red[w][ rl       * 32 + 16 + r] = acc01[q];
    red[w][(rl + 16) * 32 +      r] = acc10[q];
    red[w][(rl + 16) * 32 + 16 + r] = acc11[q];
  }
  __syncthreads();
  #pragma unroll
  for (int i = 0; i < 2; ++i) {
    int e = (int)threadIdx.x + i * 512;
    float s = red[0][e] + red[1][e] + red[2][e] + red[3][e]
            + red[4][e] + red[5][e] + red[6][e] + red[7][e];
    out[ob + (size_t)row0 * 32 + e] = s;
  }
}

extern "C" void kernel_launch(void* const* d_in, const int* in_sizes, int n_in,
                              void* d_out, int out_size, void* d_ws, size_t ws_size,
                              hipStream_t stream) {
  const float* xv   = (const float*)d_in[0];
  const float* xe   = (const float*)d_in[1];
  const float* xf   = (const float*)d_in[2];
  const float* Gv2v = (const float*)d_in[3];
  const float* Gv2e = (const float*)d_in[4];
  const float* Ge2e = (const float*)d_in[5];
  const float* Ge2f = (const float*)d_in[6];
  const float* Gf2f = (const float*)d_in[7];
  const float* Wv2v = (const float*)d_in[8];
  const float* Wv2e = (const float*)d_in[9];
  const float* We2e = (const float*)d_in[10];
  const float* We2f = (const float*)d_in[11];
  const float* Wf2f = (const float*)d_in[12];
  short* Yt  = (short*)d_ws;
  float* out = (float*)d_out;

  hipLaunchKernelGGL(build_yt, dim3(174), dim3(256), 0, stream,
                     xv, xe, xf, Wv2v, Wv2e, We2e, We2f, Wf2f, Yt);
  hipLaunchKernelGGL(gemm_skinny, dim3(813), dim3(512), 0, stream,
                     Gv2v, Gv2e, Ge2e, Ge2f, Gf2f, Yt, out);
}

// Round 9
// 294.480 us; speedup vs baseline: 1.3071x; 1.0748x over previous
//
#include <hip/hip_runtime.h>

typedef float  f32x4 __attribute__((ext_vector_type(4)));
typedef short  s16x8 __attribute__((ext_vector_type(8)));

#define PK   256   // panel K-span (floats); 1KB burst per row
#define PSTR 260   // padded LDS row stride (2-way bank alias = free)
#define TM   32    // output rows per block

typedef const __attribute__((address_space(1))) float* gas1f;
typedef __attribute__((address_space(3))) float*       las3f;

__device__ __forceinline__ short f2bf(float f) {
  unsigned u = __builtin_bit_cast(unsigned, f);
  u += 0x7FFFu + ((u >> 16) & 1u);   // round-to-nearest-even
  return (short)(u >> 16);
}

// ---------------------------------------------------------------------------
// Kernel 1: Y^T build.  Yt[c][k] = bf16( sum_d x[k][d] * W[d][c] )
// LDS-transposed epilogue: Yt written as 512B contiguous runs per column-row.
// Kpad multiple of 256, zero-filled.  Offsets (elements):
//  v2v 0 (Kpad 6144) | v2e 196608 | e2e 393216 (Kpad 12032) | e2f 778240
//  f2f 1163264 (Kpad 8192); total 1425408 elems = 2.85 MB.
// ---------------------------------------------------------------------------
__global__ __launch_bounds__(256) void build_yt(
    const float* __restrict__ xv, const float* __restrict__ xe,
    const float* __restrict__ xf,
    const float* __restrict__ Wv2v, const float* __restrict__ Wv2e,
    const float* __restrict__ We2e, const float* __restrict__ We2f,
    const float* __restrict__ Wf2f, short* __restrict__ Yt)
{
  int bid = blockIdx.x;
  const float* x; const float* W; int K, Kpad; size_t yoff;
  if (bid < 24)       { x=xv; W=Wv2v; K=6000;  Kpad=6144;  yoff=0;       }
  else if (bid < 48)  { x=xv; W=Wv2e; K=6000;  Kpad=6144;  yoff=196608;  bid-=24; }
  else if (bid < 95)  { x=xe; W=We2e; K=12000; Kpad=12032; yoff=393216;  bid-=48; }
  else if (bid < 142) { x=xe; W=We2f; K=12000; Kpad=12032; yoff=778240;  bid-=95; }
  else                { x=xf; W=Wf2f; K=8000;  Kpad=8192;  yoff=1163264; bid-=142; }

  __shared__ float Wl[32][32];
  __shared__ short sh[32][264];        // 264: 16B-aligned rows, bank-spread
  int tid = threadIdx.x;
  #pragma unroll
  for (int i = 0; i < 4; ++i) {
    int e = tid + i * 256;
    Wl[e >> 5][e & 31] = W[e];
  }
  __syncthreads();

  int row = bid * 256 + tid;           // always < Kpad
  float acc[32];
  #pragma unroll
  for (int c = 0; c < 32; ++c) acc[c] = 0.f;

  if (row < K) {
    const float* xp = x + (size_t)row * 32;
    float xr[32];
    #pragma unroll
    for (int i = 0; i < 8; ++i) {
      f32x4 v = *(const f32x4*)(xp + i * 4);
      xr[i*4+0] = v.x; xr[i*4+1] = v.y; xr[i*4+2] = v.z; xr[i*4+3] = v.w;
    }
    #pragma unroll
    for (int d = 0; d < 32; ++d) {
      float xd = xr[d];
      #pragma unroll
      for (int c = 0; c < 32; ++c) acc[c] += xd * Wl[d][c];
    }
  }
  #pragma unroll
  for (int c = 0; c < 32; ++c) sh[c][tid] = f2bf(acc[c]);
  __syncthreads();

  // coalesced store: 8 threads per Yt row; each thread 32 shorts (64B)
  int c = tid >> 3, q = tid & 7;
  const short* sp = &sh[c][q * 32];
  short* dp = Yt + yoff + (size_t)c * Kpad + (size_t)bid * 256 + q * 32;
  #pragma unroll
  for (int i = 0; i < 4; ++i)
    *(s16x8*)(dp + i * 8) = *(const s16x8*)(sp + i * 8);
}

// ---------------------------------------------------------------------------
// Kernel 2: skinny GEMM, TM=32, K-chunked (2 chunks/tile) for tail smoothing.
// 512 threads / 8 waves; R8 counted-vmcnt pipeline preserved per chunk.
// Chunk A writes out directly; chunk B writes one fp32 partial per tile.
// ---------------------------------------------------------------------------
__device__ __forceinline__ void stage_panel(
    const float* __restrict__ G, int K, int row0, int pn, int lane, int w,
    float (*panel)[TM][PSTR], int bb)
{
  if ((pn + 1) * PK <= K) {            // full panel: 1KB DMA burst per row
    const float* base = G + (size_t)row0 * K + (size_t)pn * PK;
    #pragma unroll
    for (int j = 0; j < 4; ++j) {
      int rr = 4 * w + j;              // 8 waves x 4 rows = 32
      __builtin_amdgcn_global_load_lds((gas1f)(base + (size_t)rr * K + lane * 4),
                                       (las3f)&panel[bb][rr][0], 16, 0, 2 /*nt*/);
    }
  } else {                             // tail: reg-staged, masked, zero-filled
    #pragma unroll
    for (int j = 0; j < 4; ++j) {
      int rr = 4 * w + j;
      int k = pn * PK + lane * 4;
      f32x4 v = {0.f, 0.f, 0.f, 0.f};
      if (k < K) v = *(const f32x4*)(G + (size_t)(row0 + rr) * K + k);
      *(f32x4*)&panel[bb][rr][lane * 4] = v;
    }
  }
}

__device__ __forceinline__ void loadB(const short* __restrict__ Y, int Kp,
                                      int r, int g, int w, int p, s16x8 B[2])
{
  int kg = p * PK + w * 32 + g * 8;    // wave w owns k-step w of the panel
  B[0] = *(const s16x8*)(Y + (size_t)r        * Kp + kg);
  B[1] = *(const s16x8*)(Y + (size_t)(r + 16) * Kp + kg);
}

__device__ __forceinline__ void seg_run(
    const float* __restrict__ G, const short* __restrict__ Yt,
    int K, int Kp, int row0, int p_lo, int p_hi, int lane, int w,
    float (*panel)[TM][PSTR],
    f32x4& acc00, f32x4& acc01, f32x4& acc10, f32x4& acc11)
{
  if (p_lo >= p_hi) return;
  int r = lane & 15, g = lane >> 4;
  s16x8 Bc[2], Bn[2];

  // prologue, per-wave FIFO: stage(p_lo)[4] < B(p_lo)[2] < stage(p_lo+1)[4]
  stage_panel(G, K, row0, p_lo, lane, w, panel, p_lo & 1);
  loadB(Yt, Kp, r, g, w, p_lo, Bc);
  if (p_lo + 1 < p_hi) stage_panel(G, K, row0, p_lo + 1, lane, w, panel, (p_lo + 1) & 1);

  for (int p = p_lo; p < p_hi; ++p) {
    // wait: stage(p)+B(p) done; stage(p+1) (if DMA-staged) stays in flight
    if (p + 1 < p_hi && (p + 2) * PK <= K)
      asm volatile("s_waitcnt vmcnt(4)" ::: "memory");
    else
      asm volatile("s_waitcnt vmcnt(0)" ::: "memory");
    __builtin_amdgcn_s_barrier();

    int b  = p & 1;
    int kk = w * 32 + g * 8;
    f32x4 l0 = *(const f32x4*)&panel[b][r][kk];
    f32x4 l1 = *(const f32x4*)&panel[b][r][kk + 4];
    f32x4 h0 = *(const f32x4*)&panel[b][r + 16][kk];
    f32x4 h1 = *(const f32x4*)&panel[b][r + 16][kk + 4];
    s16x8 alo, ahi;
    alo[0]=f2bf(l0.x); alo[1]=f2bf(l0.y); alo[2]=f2bf(l0.z); alo[3]=f2bf(l0.w);
    alo[4]=f2bf(l1.x); alo[5]=f2bf(l1.y); alo[6]=f2bf(l1.z); alo[7]=f2bf(l1.w);
    ahi[0]=f2bf(h0.x); ahi[1]=f2bf(h0.y); ahi[2]=f2bf(h0.z); ahi[3]=f2bf(h0.w);
    ahi[4]=f2bf(h1.x); ahi[5]=f2bf(h1.y); ahi[6]=f2bf(h1.z); ahi[7]=f2bf(h1.w);
    acc00 = __builtin_amdgcn_mfma_f32_16x16x32_bf16(alo, Bc[0], acc00, 0, 0, 0);
    acc01 = __builtin_amdgcn_mfma_f32_16x16x32_bf16(alo, Bc[1], acc01, 0, 0, 0);
    acc10 = __builtin_amdgcn_mfma_f32_16x16x32_bf16(ahi, Bc[0], acc10, 0, 0, 0);
    acc11 = __builtin_amdgcn_mfma_f32_16x16x32_bf16(ahi, Bc[1], acc11, 0, 0, 0);

    bool have_next = (p + 1 < p_hi);
    if (have_next) loadB(Yt, Kp, r, g, w, p + 1, Bn);   // flies across barrier

    asm volatile("s_waitcnt lgkmcnt(0)" ::: "memory");
    __builtin_amdgcn_sched_barrier(0);
    __builtin_amdgcn_s_barrier();      // all waves done reading buf b
    if (p + 2 < p_hi) stage_panel(G, K, row0, p + 2, lane, w, panel, b);

    if (have_next) { Bc[0] = Bn[0]; Bc[1] = Bn[1]; }
  }
  __syncthreads();                     // chunk epilogue: full drain
}

// grid = 1438:
//  [0,250)    zfA: Ge2f[0,40)                 -> out   (tile = bid)
//  [250,500)  zfB: Ge2f[40,47)+Gf2f[0,32)     -> part[tile]
//  [500,875)  zeB: Ge2e[11,47)                -> part[250+tile]
//  [875,1250) zeA: Gv2e[0,24)+Ge2e[0,11)      -> out
//  [1250,1438) zv: Gv2v[0,24)                 -> out
__global__ __launch_bounds__(512) void gemm_skinny(
    const float* __restrict__ Gv2v, const float* __restrict__ Gv2e,
    const float* __restrict__ Ge2e, const float* __restrict__ Ge2f,
    const float* __restrict__ Gf2f, const short* __restrict__ Yt,
    float* __restrict__ part, float* __restrict__ out)
{
  __shared__ float panel[2][TM][PSTR];   // 66,560 B; reused for reduce

  int bid  = blockIdx.x;
  int lane = threadIdx.x & 63, w = threadIdx.x >> 6;

  const float *Ga, *Gb = nullptr; const short *Ya, *Yb = nullptr;
  int Ka, Kpa, alo, ahi, Kb = 0, Kpb = 0, blo = 0, bhi = 0, tile, row0;
  float* dst;
  if (bid < 250) {                     // zfA (direct)
    tile = bid; row0 = tile * TM;
    Ga = Ge2f; Ya = Yt + 778240; Ka = 12000; Kpa = 12032; alo = 0;  ahi = 40;
    dst = out + 576000 + (size_t)tile * 1024;
  } else if (bid < 500) {              // zfB (partial)
    tile = bid - 250; row0 = tile * TM;
    Ga = Ge2f; Ya = Yt + 778240;  Ka = 12000; Kpa = 12032; alo = 40; ahi = 47;
    Gb = Gf2f; Yb = Yt + 1163264; Kb = 8000;  Kpb = 8192;  blo = 0;  bhi = 32;
    dst = part + (size_t)tile * 1024;
  } else if (bid < 875) {              // zeB (partial)
    tile = bid - 500; row0 = tile * TM;
    Ga = Ge2e; Ya = Yt + 393216; Ka = 12000; Kpa = 12032; alo = 11; ahi = 47;
    dst = part + (size_t)(250 + tile) * 1024;
  } else if (bid < 1250) {             // zeA (direct)
    tile = bid - 875; row0 = tile * TM;
    Ga = Gv2e; Ya = Yt + 196608; Ka = 6000;  Kpa = 6144;  alo = 0; ahi = 24;
    Gb = Ge2e; Yb = Yt + 393216; Kb = 12000; Kpb = 12032; blo = 0; bhi = 11;
    dst = out + 192000 + (size_t)tile * 1024;
  } else {                             // zv (direct)
    tile = bid - 1250; row0 = tile * TM;
    if (row0 + TM > 6000) row0 = 6000 - TM;   // overlap tile (same values)
    Ga = Gv2v; Ya = Yt; Ka = 6000; Kpa = 6144; alo = 0; ahi = 24;
    dst = out + (size_t)row0 * 32;
  }

  f32x4 acc00 = {0.f,0.f,0.f,0.f}, acc01 = {0.f,0.f,0.f,0.f};
  f32x4 acc10 = {0.f,0.f,0.f,0.f}, acc11 = {0.f,0.f,0.f,0.f};
  seg_run(Ga, Ya, Ka, Kpa, row0, alo, ahi, lane, w, panel,
          acc00, acc01, acc10, acc11);
  if (Gb)
    seg_run(Gb, Yb, Kb, Kpb, row0, blo, bhi, lane, w, panel,
            acc00, acc01, acc10, acc11);

  // cross-wave reduce (C/D layout: col = lane&15, row = (lane>>4)*4+reg)
  float (*red)[1024] = (float (*)[1024])panel;   // 8x1024 f, aliases panel
  int r = lane & 15, g = lane >> 4;
  #pragma unroll
  for (int q = 0; q < 4; ++q) {
    int rl = g * 4 + q;
    red[w][ rl       * 32 +      r] = acc00[q];
    red[w][ rl       * 32 + 16 + r] = acc01[q];
    red[w][(rl + 16) * 32 +      r] = acc10[q];
    red[w][(rl + 16) * 32 + 16 + r] = acc11[q];
  }
  __syncthreads();
  #pragma unroll
  for (int i = 0; i < 2; ++i) {
    int e = (int)threadIdx.x + i * 512;
    float s = red[0][e] + red[1][e] + red[2][e] + red[3][e]
            + red[4][e] + red[5][e] + red[6][e] + red[7][e];
    dst[e] = s;
  }
}

// out += part.  zf: 250 tiles (out+576000); ze: 375 tiles (out+192000).
__global__ __launch_bounds__(256) void reduce_partials(
    float* __restrict__ out, const float* __restrict__ part)
{
  int e = blockIdx.x * 256 + threadIdx.x;     // grid 2500 -> 640000
  if (e < 256000) {
    out[576000 + e] += part[e];
  } else {
    int e2 = e - 256000;                      // < 384000
    out[192000 + e2] += part[256000 + e2];
  }
}

extern "C" void kernel_launch(void* const* d_in, const int* in_sizes, int n_in,
                              void* d_out, int out_size, void* d_ws, size_t ws_size,
                              hipStream_t stream) {
  const float* xv   = (const float*)d_in[0];
  const float* xe   = (const float*)d_in[1];
  const float* xf   = (const float*)d_in[2];
  const float* Gv2v = (const float*)d_in[3];
  const float* Gv2e = (const float*)d_in[4];
  const float* Ge2e = (const float*)d_in[5];
  const float* Ge2f = (const float*)d_in[6];
  const float* Gf2f = (const float*)d_in[7];
  const float* Wv2v = (const float*)d_in[8];
  const float* Wv2e = (const float*)d_in[9];
  const float* We2e = (const float*)d_in[10];
  const float* We2f = (const float*)d_in[11];
  const float* Wf2f = (const float*)d_in[12];
  short* Yt   = (short*)d_ws;
  float* part = (float*)((char*)d_ws + 2850816);   // 625 x 1024 f32 = 2.56 MB
  float* out  = (float*)d_out;

  hipLaunchKernelGGL(build_yt, dim3(174), dim3(256), 0, stream,
                     xv, xe, xf, Wv2v, Wv2e, We2e, We2f, Wf2f, Yt);
  hipLaunchKernelGGL(gemm_skinny, dim3(1438), dim3(512), 0, stream,
                     Gv2v, Gv2e, Ge2e, Ge2f, Gf2f, Yt, part, out);
  hipLaunchKernelGGL(reduce_partials, dim3(2500), dim3(256), 0, stream,
                     out, part);
}